// Round 14
// baseline (368.566 us; speedup 1.0000x reference)
//
#include <hip/hip_runtime.h>
#include <hip/hip_bf16.h>

#define B    16
#define NA   25200
#define NCH  85
#define NCLS 80
#define K    2048
#define CAP  4096
#define ACAP 4096
#define DET  300
#define TILE 64
#define NTILES 394                     // ceil(25200/64)
#define PBLK 64                        // k_pairs blocks per image
#define LBUF 2304                      // k_pairs LDS buffer
#define SBASE  0x3FD0000000000000ULL   // bits of 0.25 (double)
#define SSHIFT 42                      // -> 2048 bins over (0.25, 1.0)

typedef unsigned long long u64;
typedef unsigned int u32;
typedef unsigned short u16;

__device__ __forceinline__ double dsig(float x) { return 1.0 / (1.0 + exp(-(double)x)); }
__device__ __forceinline__ float  fsig(float x) { return 1.0f / (1.0f + __expf(-x)); }

// ---- Pass 1: full sweep with register-prefetch double buffering.
// Partial histograms (plain stores) + per-anchor u16 round-up max-score.
__global__ void __launch_bounds__(256) k_hist(const float* __restrict__ head,
                                              u32* __restrict__ phist, u16* __restrict__ smax16) {
    __shared__ float rows[TILE * NCH];     // 21760 B
    __shared__ int h[2048];                // 8192 B
    __shared__ float smaxT[TILE][4];       // 1024 B
    int tid = threadIdx.x;
    int hblk = gridDim.x;
    for (int i = tid; i < 2048; i += 256) h[i] = 0;
    int img = blockIdx.y;
    const float* ibase = head + (size_t)img * NA * NCH;

    float4 pf[6];
    int tile = blockIdx.x;
    {                                      // prefetch first tile
        int a0 = tile * TILE;
        int na = NA - a0; if (na > TILE) na = TILE;
        int nf4 = (na * NCH) >> 2;
        const float4* src = (const float4*)(ibase + (size_t)a0 * NCH);
        #pragma unroll
        for (int u = 0; u < 6; ++u) { int i = tid + u * 256; pf[u] = (i < nf4) ? src[i] : make_float4(0.f,0.f,0.f,0.f); }
    }
    for (; tile < NTILES; tile += hblk) {
        int a0 = tile * TILE;
        int na = NA - a0; if (na > TILE) na = TILE;
        int nf4 = (na * NCH) >> 2;
        __syncthreads();                   // prev iteration fully done with rows
        #pragma unroll
        for (int u = 0; u < 6; ++u) { int i = tid + u * 256; if (i < nf4) ((float4*)rows)[i] = pf[u]; }
        __syncthreads();
        int nt = tile + hblk;              // issue next tile's loads under compute
        if (nt < NTILES) {
            int a0n = nt * TILE;
            int nan_ = NA - a0n; if (nan_ > TILE) nan_ = TILE;
            int nf4n = (nan_ * NCH) >> 2;
            const float4* srcn = (const float4*)(ibase + (size_t)a0n * NCH);
            #pragma unroll
            for (int u = 0; u < 6; ++u) { int i = tid + u * 256; pf[u] = (i < nf4n) ? srcn[i] : make_float4(0.f,0.f,0.f,0.f); }
        }
        for (int t = tid; t < 4 * na; t += 256) {        // 4 threads per anchor
            int a = t >> 2, q = t & 3;
            float fo = fsig(rows[a * NCH + 4]);
            float lm = 0.0f;
            if (fo > 0.25f) {
                float qq = 0.24975f / fo;                         // (0.2497, 0.999)
                float cth = __logf(qq) - __logf(1.0f - qq);       // logit precheck
                int c0 = q * 20;
                for (int c = c0; c < c0 + 20; ++c) {
                    float cl = rows[a * NCH + 5 + c];
                    if (cl > cth) {
                        float sc = fo * fsig(cl);
                        lm = fmaxf(lm, sc);
                        if (sc > 0.25f) {
                            u64 bits = (u64)__double_as_longlong((double)sc);
                            int bb = (int)((bits - SBASE) >> SSHIFT);
                            if (bb > 2047) bb = 2047;
                            atomicAdd(&h[bb], 1);
                        }
                    }
                }
            }
            smaxT[a][q] = lm;
        }
        __syncthreads();
        for (int t = tid; t < na; t += 256) {
            float m = fmaxf(fmaxf(smaxT[t][0], smaxT[t][1]), fmaxf(smaxT[t][2], smaxT[t][3]));
            u32 mb = __float_as_uint(m);
            smax16[(size_t)img * NA + a0 + t] = (u16)((mb + 0xFFFFu) >> 16);  // round UP
        }
    }
    __syncthreads();
    u32* dst = phist + ((size_t)img * hblk + blockIdx.x) * 2048;
    for (int i = tid; i < 2048; i += 256) dst[i] = (u32)h[i];
}

// ---- Pass 2: fused partial-hist reduce + cut-bin search (+ cnt/cntA zeroing,
// replacing the separate memset dispatch; runs before k_screen/k_pairs). ----
__global__ void __launch_bounds__(256) k_redcut(const u32* __restrict__ phist,
                                                u64* __restrict__ cut, int hblk,
                                                u32* __restrict__ cnt, u32* __restrict__ cntA) {
    __shared__ int h[2048];
    int img = blockIdx.x, tid = threadIdx.x;
    if (tid == 64) cnt[img] = 0;
    if (tid == 65) cntA[img] = 0;
    for (int bin = tid; bin < 2048; bin += 256) {
        u32 s = 0;
        for (int p = 0; p < hblk; ++p) s += phist[((size_t)img * hblk + p) * 2048 + bin];
        h[bin] = (int)s;
    }
    __syncthreads();
    if (tid < 64) {
        int lane = tid;
        int cum = 0; u64 cb = 0;
        for (int ch = 0; ch < 32; ++ch) {
            int pfx = h[2047 - ch * 64 - lane];
            for (int d = 1; d < 64; d <<= 1) { int o = __shfl_up(pfx, d, 64); if (lane >= d) pfx += o; }
            u64 ball = __ballot(cum + pfx >= K);
            if (ball) {
                int fl = __ffsll((long long)ball) - 1;
                int bin = 2047 - ch * 64 - fl;
                cb = (bin >= 1) ? (SBASE + ((u64)(bin - 1) << SSHIFT)) : 0ULL;  // one-bin margin
                break;
            }
            cum += __shfl(pfx, 63, 64);
        }
        if (lane == 0) cut[img] = cb;
    }
}

// ---- Pass 3a: screen anchors by smax upper bound; compact survivor list ----
__global__ void __launch_bounds__(256) k_screen(const u16* __restrict__ smax16, const u64* __restrict__ cut,
                                                u32* __restrict__ cntA, int* __restrict__ alist) {
    __shared__ int lcnt, lbase, buf[256];
    int img = blockIdx.y;
    int a = blockIdx.x * 256 + threadIdx.x;
    if (threadIdx.x == 0) lcnt = 0;
    __syncthreads();
    u64 cutb = cut[img];
    float cutf = cutb ? (float)__longlong_as_double((long long)cutb) : 0.25f;
    float pre = fmaxf(0.2489f, cutf * 0.999f);
    if (a < NA) {
        float fup = __uint_as_float(((u32)smax16[(size_t)img * NA + a]) << 16);
        if (fup >= pre) buf[atomicAdd(&lcnt, 1)] = a;
    }
    __syncthreads();
    if (threadIdx.x == 0 && lcnt) lbase = atomicAdd(&cntA[img], (u32)lcnt);
    __syncthreads();
    for (int i = threadIdx.x; i < lcnt; i += 256) {
        int pos = lbase + i;
        if (pos < ACAP) alist[img * ACAP + pos] = buf[i];
    }
}

// ---- Pass 3b: pairs with per-block LDS compaction ----
__global__ void __launch_bounds__(256) k_pairs(const float* __restrict__ head, const u64* __restrict__ cut,
                                               const u32* __restrict__ cntA, const int* __restrict__ alist,
                                               u32* __restrict__ cnt, u64* __restrict__ sb, u32* __restrict__ si) {
    __shared__ u64 lsb[LBUF];
    __shared__ u32 lsi[LBUF];
    __shared__ u32 lcnt, lbase;
    int img = blockIdx.y;
    int tid = threadIdx.x;
    u64 cutb = cut[img];
    float cutf = cutb ? (float)__longlong_as_double((long long)cutb) : 0.25f;
    float pre = fmaxf(0.2489f, cutf * 0.999f);
    int nsur = (int)cntA[img]; if (nsur > ACAP) nsur = ACAP;
    int npairs = nsur * NCLS;
    u64* sbi = sb + (size_t)img * CAP;
    u32* sii = si + (size_t)img * CAP;
    const float* ibase = head + (size_t)img * NA * NCH;
    if (tid == 0) lcnt = 0;
    __syncthreads();

    int base = blockIdx.x * 256;
    int ntrip = (npairs > base) ? (npairs - base + PBLK * 256 - 1) / (PBLK * 256) : 0;
    for (int t = 0; t < ntrip; ++t) {
        int p = base + tid + t * PBLK * 256;
        if (p < npairs) {
            int ai = (int)((u32)p / NCLS);
            int c  = p - ai * NCLS;
            int a  = alist[img * ACAP + ai];
            const float* row = ibase + (size_t)a * NCH;
            float o = row[4], cl = row[5 + c];
            float s32 = fsig(o) * fsig(cl);
            if (s32 >= pre) {
                double sc = dsig(o) * dsig(cl);        // exact f64 decision
                if (sc > 0.25) {
                    u64 bits = (u64)__double_as_longlong(sc);
                    if (bits >= cutb) {
                        u32 pos = atomicAdd(&lcnt, 1u);
                        if (pos < LBUF) { lsb[pos] = bits; lsi[pos] = (u32)(a * NCLS + c); }
                    }
                }
            }
        }
        __syncthreads();
        if (lcnt >= 2048) {
            u32 n = lcnt; if (n > LBUF) n = LBUF;
            if (tid == 0) lbase = atomicAdd(&cnt[img], n);
            __syncthreads();
            for (u32 i = tid; i < n; i += 256) {
                u32 pos = lbase + i;
                if (pos < CAP) { sbi[pos] = lsb[i]; sii[pos] = lsi[i]; }
            }
            __syncthreads();
            if (tid == 0) lcnt = 0;
            __syncthreads();
        }
    }
    u32 n = lcnt; if (n > LBUF) n = LBUF;
    if (n) {
        if (tid == 0) lbase = atomicAdd(&cnt[img], n);
        __syncthreads();
        for (u32 i = tid; i < n; i += 256) {
            u32 pos = lbase + i;
            if (pos < CAP) { sbi[pos] = lsb[i]; sii[pos] = lsi[i]; }
        }
    }
}

// ---- Pass 4 (fused): counting sort -> decode (f64) -> SoA LDS offset boxes ->
// parallel stable seg build -> REGISTER-RESIDENT per-class wave greedy NMS
// (shfl broadcast, no LDS in loop) + cross-class cert (exact fallback) -> emit. ----
__global__ void __launch_bounds__(1024) k_snms(const float* __restrict__ head,
        const float* __restrict__ grid, const float* __restrict__ ag, const float* __restrict__ stv,
        const u32* __restrict__ cntArr, const u64* __restrict__ sb, const u32* __restrict__ si,
        float* __restrict__ out) {
    __shared__ double obm[4][K];      // 65536 B SoA; sort phase aliases inside
    __shared__ u64 mask[32], imask[32];
    __shared__ u16 labs[K];           // 4096 B
    __shared__ u16 seg[K];            // 4096 B (class-grouped slot ids, score order)
    __shared__ u32 chunkcnt[32][NCLS];// 10240 B: per-chunk class counts -> positions
    __shared__ int clsbase[NCLS + 1];
    __shared__ int clscnt[NCLS];
    __shared__ double red[16], red2[16];
    __shared__ double s_offb;
    __shared__ int wpfx[33];
    __shared__ int viol;
    __shared__ u32 segtot[32];

    int img = blockIdx.x;
    int tid = threadIdx.x;
    int lane = tid & 63, wv = tid >> 6;

    // sort-phase aliases inside obm: TA 32KB | TI 16KB | h2 8KB | cntb 8KB
    u64* TA   = (u64*)obm;            // [4096]
    u32* TI   = (u32*)(TA + 4096);    // [4096]
    u32* h2   = (u32*)(TI + 4096);    // [2048]
    u32* cntb = (u32*)(h2 + 2048);    // [2048]
    u32* tmp  = TI;                   // scan scratch (TI unused until scatter)

    const u64* A = sb + (size_t)img * CAP;
    const u32* I = si + (size_t)img * CAP;
    int cnt = (int)cntArr[img]; if (cnt > CAP) cnt = CAP;

    // 1. bin histogram of candidates (exact f64 top-11-bit bins)
    for (int b = tid; b < 2048; b += 1024) h2[b] = 0;
    __syncthreads();
    for (int e = tid; e < cnt; e += 1024) {
        u64 bits = A[e];
        int b = (int)((bits - SBASE) >> SSHIFT);
        b = b < 0 ? 0 : (b > 2047 ? 2047 : b);
        atomicAdd(&h2[b], 1u);
    }
    __syncthreads();
    // 2. suffix-sum -> start positions (descending bin order); snapshot counts
    for (int s = wv; s < 32; s += 16) {
        int r = s * 64 + lane;
        u32 v = h2[2047 - r];
        cntb[2047 - r] = v;
        u32 p = v;
        for (int d = 1; d < 64; d <<= 1) { u32 o = __shfl_up(p, d, 64); if (lane >= d) p += o; }
        if (lane == 63) segtot[s] = p;
        tmp[r] = p - v;
    }
    __syncthreads();
    if (tid < 32) {
        u32 v = segtot[tid], p = v;
        for (int d = 1; d < 32; d <<= 1) { u32 o = __shfl_up(p, d, 64); if (lane >= d) p += o; }
        segtot[tid] = p - v;
    }
    __syncthreads();
    for (int s = wv; s < 32; s += 16) {
        int r = s * 64 + lane;
        h2[2047 - r] = tmp[r] + segtot[s];
    }
    __syncthreads();
    // 3. init pad + scatter (within-bin order arbitrary)
    for (int e = tid; e < 4096; e += 1024) if (e >= cnt) { TA[e] = 0ULL; TI[e] = 0xFFFFFFFFu; }
    __syncthreads();
    for (int e = tid; e < cnt; e += 1024) {
        u64 bits = A[e]; u32 idx = I[e];
        int b = (int)((bits - SBASE) >> SSHIFT);
        b = b < 0 ? 0 : (b > 2047 ? 2047 : b);
        u32 slot = atomicAdd(&h2[b], 1u);
        if (slot < 4096u) { TA[slot] = bits; TI[slot] = idx; }
    }
    __syncthreads();
    // 4. parallel in-bin rank: each element finds its exact sorted slot
    u64 rb[4]; u32 ri[4]; int rp[4];
    #pragma unroll
    for (int s4 = 0; s4 < 4; ++s4) {
        int p = tid + s4 * 1024;
        rp[s4] = -1;
        if (p < cnt) {
            u64 kb = TA[p]; u32 ki = TI[p];
            int b = (int)((kb - SBASE) >> SSHIFT);
            b = b < 0 ? 0 : (b > 2047 ? 2047 : b);
            int en = (int)h2[b];
            int st = en - (int)cntb[b];
            int r = st;
            for (int j = st; j < en; ++j) {
                u64 b2 = TA[j]; u32 i2 = TI[j];
                if (b2 > kb || (b2 == kb && i2 < ki)) ++r;
            }
            rb[s4] = kb; ri[s4] = ki; rp[s4] = r;
        }
    }
    __syncthreads();
    #pragma unroll
    for (int s4 = 0; s4 < 4; ++s4)
        if (rp[s4] >= 0 && rp[s4] < 4096) { TA[rp[s4]] = rb[s4]; TI[rp[s4]] = ri[s4]; }
    __syncthreads();
    // 5. top-2048 to registers
    u64 sv[2]; u32 fidx[2];
    sv[0] = TA[tid];        fidx[0] = TI[tid];
    sv[1] = TA[1024 + tid]; fidx[1] = TI[1024 + tid];
    __syncthreads();                    // TA/TI dead; obm reusable

    // --- decode (exact f64) + chunk class counts ---
    if (tid < NCLS) clscnt[tid] = 0;
    if (tid == 0) viol = 0;
    for (int i = tid; i < 32 * NCLS; i += 1024) ((u32*)chunkcnt)[i] = 0;
    double bx[2][4];
    int lab[2];
    bool val[2];
    double lmax = -1e300, lmin = 1e300;
    __syncthreads();
    #pragma unroll
    for (int q = 0; q < 2; ++q) {
        int slot = q * 1024 + tid;
        val[q] = (sv[q] != 0ULL);
        bx[q][0] = bx[q][1] = bx[q][2] = bx[q][3] = 0.0;
        lab[q] = 0;
        if (val[q]) {
            int a = (int)(fidx[q] / NCLS);
            lab[q] = (int)(fidx[q] % NCLS);
            const float* row = head + ((size_t)img * NA + a) * NCH;
            double p0 = dsig(row[0]), p1 = dsig(row[1]), p2 = dsig(row[2]), p3 = dsig(row[3]);
            double st = (double)stv[a];
            double xc = (p0 * 2.0 - 0.5 + (double)grid[a * 2 + 0]) * st;
            double yc = (p1 * 2.0 - 0.5 + (double)grid[a * 2 + 1]) * st;
            double w = p2 * 2.0; w = (w * w) * (double)ag[a * 2 + 0];
            double h = p3 * 2.0; h = (h * h) * (double)ag[a * 2 + 1];
            bx[q][0] = xc - w * 0.5; bx[q][1] = yc - h * 0.5;
            bx[q][2] = xc + w * 0.5; bx[q][3] = yc + h * 0.5;
            lmax = fmax(lmax, fmax(fmax(bx[q][0], bx[q][1]), fmax(bx[q][2], bx[q][3])));
            lmin = fmin(lmin, fmin(fmin(bx[q][0], bx[q][1]), fmin(bx[q][2], bx[q][3])));
            atomicAdd(&clscnt[lab[q]], 1);
            atomicAdd(&chunkcnt[slot >> 6][lab[q]], 1u);
        }
        labs[slot] = val[q] ? (u16)lab[q] : (u16)0xFFFF;
    }
    for (int d = 1; d < 64; d <<= 1) {
        lmax = fmax(lmax, __shfl_xor(lmax, d, 64));
        lmin = fmin(lmin, __shfl_xor(lmin, d, 64));
    }
    if (lane == 0) { red[wv] = lmax; red2[wv] = lmin; }
    u64 b0m = __ballot(val[0]), b1m = __ballot(val[1]);
    if (lane == 0) { mask[wv] = b0m; imask[wv] = b0m; mask[16 + wv] = b1m; imask[16 + wv] = b1m; }
    __syncthreads();
    if (tid == 0) {
        double m = red[0], mn = red2[0];
        for (int w2 = 1; w2 < 16; ++w2) { m = fmax(m, red[w2]); mn = fmin(mn, red2[w2]); }
        s_offb = m + 1.0;
        if (m + 2.0 + mn < 0.0) viol = 1;   // |dclass|>=2 overlap possible -> fallback
    }
    __syncthreads();
    double offb = s_offb;

    double oB[2][4], aR[2];
    #pragma unroll
    for (int q = 0; q < 2; ++q) {
        double off = offb * (double)lab[q];
        oB[q][0] = bx[q][0] + off; oB[q][1] = bx[q][1] + off;
        oB[q][2] = bx[q][2] + off; oB[q][3] = bx[q][3] + off;
        aR[q] = (oB[q][2] - oB[q][0]) * (oB[q][3] - oB[q][1]);
        int slot = q * 1024 + tid;
        obm[0][slot] = oB[q][0]; obm[1][slot] = oB[q][1];
        obm[2][slot] = oB[q][2]; obm[3][slot] = oB[q][3];
    }
    __syncthreads();

    // class-count exclusive scan -> clsbase[0..80]
    if (tid < 64) {
        int c0 = clscnt[lane];
        int c1 = (lane < NCLS - 64) ? clscnt[64 + lane] : 0;
        int p0 = c0;
        for (int d = 1; d < 64; d <<= 1) { int o = __shfl_up(p0, d, 64); if (lane >= d) p0 += o; }
        int tot0 = __shfl(p0, 63, 64);
        int p1 = c1;
        for (int d = 1; d < 64; d <<= 1) { int o = __shfl_up(p1, d, 64); if (lane >= d) p1 += o; }
        clsbase[lane] = p0 - c0;
        if (lane < NCLS - 64) clsbase[64 + lane] = tot0 + p1 - c1;
        if (lane == 63) clsbase[NCLS] = tot0 + __shfl(p1, NCLS - 64 - 1, 64);
    }
    __syncthreads();

    // chunkcnt -> chunk start positions (per class, chunks in slot order)
    if (tid < NCLS) {
        int running = clsbase[tid];
        for (int ch = 0; ch < 32; ++ch) {
            u32 t = chunkcnt[ch][tid];
            chunkcnt[ch][tid] = (u32)running;
            running += (int)t;
        }
    }
    __syncthreads();

    // stable seg build: rank within own chunk via shfl_up compare loop
    #pragma unroll
    for (int q = 0; q < 2; ++q) {
        int cl = val[q] ? lab[q] : -1;
        int rank = 0;
        for (int d = 1; d < 64; ++d) {
            int oc = __shfl_up(cl, d, 64);
            if (lane >= d && oc == cl) ++rank;
        }
        if (val[q]) {
            int slot = q * 1024 + tid;
            seg[chunkcnt[slot >> 6][cl] + rank] = (u16)slot;
        }
    }
    __syncthreads();

    // --- per-class greedy (one wave per class; register-resident, shfl broadcast) ---
    for (int k5 = 0; k5 < 5; ++k5) {
        int c = wv * 5 + k5;
        int cbase = clsbase[c];
        int m = clsbase[c + 1] - cbase;
        if (m <= 1) continue;
        if (m <= 64) {
            int s_l = (lane < m) ? (int)seg[cbase + lane] : -1;
            double e0 = 0, e1 = 0, e2 = 0, e3 = 0, ea = 0;
            if (s_l >= 0) {
                e0 = obm[0][s_l]; e1 = obm[1][s_l];
                e2 = obm[2][s_l]; e3 = obm[3][s_l];
                ea = (e2 - e0) * (e3 - e1);
            }
            u64 am = (m >= 64) ? ~0ULL : ((1ULL << m) - 1ULL);
            for (int k = 0; k < m; ++k) {
                if (!((am >> k) & 1ULL)) continue;          // uniform (am uniform)
                double k0 = __shfl(e0, k, 64), k1 = __shfl(e1, k, 64);
                double k2 = __shfl(e2, k, 64), k3 = __shfl(e3, k, 64);
                double ka = __shfl(ea, k, 64);
                double ww = fmax(fmin(k2, e2) - fmax(k0, e0), 0.0);
                double hh = fmax(fmin(k3, e3) - fmax(k1, e1), 0.0);
                double inter = ww * hh;
                bool sup = (lane > k) && ((am >> lane) & 1ULL) &&
                           (inter > 0.45 * (ka + ea - inter + 1e-7));
                am &= ~__ballot(sup);
            }
            if (s_l >= 0 && !((am >> lane) & 1ULL))
                atomicAnd(&mask[s_l >> 6], ~(1ULL << (s_l & 63)));
        } else {
            // LDS fallback for oversized classes (rare)
            for (int k = cbase + 1; k < cbase + m; ++k) {
                int s = (int)seg[k];
                double c0 = obm[0][s], c1 = obm[1][s];
                double c2v = obm[2][s], c3 = obm[3][s];
                double ca = (c2v - c0) * (c3 - c1);
                bool sup = false;
                for (int j = cbase + lane; j < k; j += 64) {
                    int t = (int)seg[j];
                    if ((mask[t >> 6] >> (t & 63)) & 1ULL) {
                        double b0 = obm[0][t], b1 = obm[1][t];
                        double b2 = obm[2][t], b3 = obm[3][t];
                        double ww = fmax(fmin(c2v, b2) - fmax(c0, b0), 0.0);
                        double hh = fmax(fmin(c3, b3) - fmax(c1, b1), 0.0);
                        double inter = ww * hh;
                        double aj = (b2 - b0) * (b3 - b1);
                        if (inter > 0.45 * (ca + aj - inter + 1e-7)) sup = true;
                    }
                }
                if (__ballot(sup)) {
                    if (lane == 0) atomicAnd(&mask[s >> 6], ~(1ULL << (s & 63)));
                }
            }
        }
    }
    __syncthreads();

    // --- certification vs adjacent classes (conservative 0.42 f32) ---
    #pragma unroll
    for (int q = 0; q < 2; ++q) {
        int s = q * 1024 + tid;
        if ((mask[s >> 6] >> (s & 63)) & 1ULL) {
            int myc = (int)labs[s];
            float c0 = (float)obm[0][s], c1 = (float)obm[1][s];
            float c2v = (float)obm[2][s], c3 = (float)obm[3][s];
            float ca = (c2v - c0) * (c3 - c1);
            #pragma unroll
            for (int dd = 0; dd < 2; ++dd) {
                int cc = myc + (dd ? 1 : -1);
                if (cc < 0 || cc >= NCLS) continue;
                int je = clsbase[cc + 1];
                for (int j = clsbase[cc]; j < je; ++j) {
                    int t = (int)seg[j];
                    if (t > s) {
                        float b0 = (float)obm[0][t], b1 = (float)obm[1][t];
                        float b2 = (float)obm[2][t], b3 = (float)obm[3][t];
                        float ww = fmaxf(fminf(c2v, b2) - fmaxf(c0, b0), 0.f);
                        float hh = fmaxf(fminf(c3, b3) - fmaxf(c1, b1), 0.f);
                        float inter = ww * hh;
                        float aj = (b2 - b0) * (b3 - b1);
                        if (inter > 0.42f * (ca + aj - inter + 1e-7f)) viol = 1;
                    }
                }
            }
        }
    }
    __syncthreads();

    // --- fallback: exact sequential greedy (cold; cert guarantees exactness) ---
    if (viol) {
        if (tid < 32) mask[tid] = imask[tid];
        bool alive[2]; alive[0] = val[0]; alive[1] = val[1];
        __syncthreads();
        int i = -1, kc = 0;
        while (true) {
            int start = i + 1;
            if (start >= K) break;
            int w = start >> 6;
            u64 m = mask[w] & (~0ULL << (start & 63));
            while (m == 0ULL) { if (++w >= 32) break; m = mask[w]; }
            if (w >= 32) break;
            i = (w << 6) + __ffsll((long long)m) - 1;
            ++kc;
            if (kc >= DET) break;
            double bi0 = obm[0][i], bi1 = obm[1][i];
            double bi2 = obm[2][i], bi3 = obm[3][i];
            double ai = (bi2 - bi0) * (bi3 - bi1);
            #pragma unroll
            for (int q = 0; q < 2; ++q) {
                int slot = q * 1024 + tid;
                double w_ = fmax(fmin(bi2, oB[q][2]) - fmax(bi0, oB[q][0]), 0.0);
                double h_ = fmax(fmin(bi3, oB[q][3]) - fmax(bi1, oB[q][1]), 0.0);
                double inter = w_ * h_;
                bool sup = inter > 0.45 * (ai + aR[q] - inter + 1e-7);
                if (alive[q] && slot > i && sup) {
                    alive[q] = false;
                    atomicAnd(&mask[slot >> 6], ~(1ULL << (slot & 63)));
                }
            }
            __syncthreads();
        }
        __syncthreads();
    }

    // --- emit ---
    if (tid == 0) {
        int s = 0;
        for (int w2 = 0; w2 < 32; ++w2) { wpfx[w2] = s; s += __popcll(mask[w2]); }
        wpfx[32] = s;
    }
    __syncthreads();
    int total = wpfx[32]; if (total > DET) total = DET;

    float* bo  = out + (size_t)img * DET * 4;
    float* so_ = out + (size_t)B * DET * 4 + (size_t)img * DET;
    float* lo  = out + (size_t)B * DET * 5 + (size_t)img * DET;
    #pragma unroll
    for (int q = 0; q < 2; ++q) {
        int slot = q * 1024 + tid;
        int w = slot >> 6, bpos = slot & 63;
        if ((mask[w] >> bpos) & 1ULL) {
            int r = wpfx[w] + __popcll(mask[w] & ((1ULL << bpos) - 1ULL));
            if (r < DET) {
                bo[r * 4 + 0] = (float)bx[q][0]; bo[r * 4 + 1] = (float)bx[q][1];
                bo[r * 4 + 2] = (float)bx[q][2]; bo[r * 4 + 3] = (float)bx[q][3];
                so_[r] = (float)__longlong_as_double((long long)sv[q]);
                lo[r] = (float)lab[q];
            }
        }
    }
    if (tid >= total && tid < DET) {
        bo[tid * 4 + 0] = 0.f; bo[tid * 4 + 1] = 0.f;
        bo[tid * 4 + 2] = 0.f; bo[tid * 4 + 3] = 0.f;
        so_[tid] = -1.0f; lo[tid] = -1.0f;
    }
}

extern "C" void kernel_launch(void* const* d_in, const int* in_sizes, int n_in,
                              void* d_out, int out_size, void* d_ws, size_t ws_size,
                              hipStream_t stream) {
    const float* head = (const float*)d_in[0];   // [16,25200,85]
    const float* grid = (const float*)d_in[1];   // [25200,2]
    const float* ag   = (const float*)d_in[2];   // [25200,2]
    const float* stv  = (const float*)d_in[3];   // [25200,1]
    float* out = (float*)d_out;
    char* ws = (char*)d_ws;

    u64* sb     = (u64*)(ws + 0);                // 16*4096*8 = 524288
    u32* si     = (u32*)(ws + 524288);           // 262144
    int* alist  = (int*)(ws + 786432);           // 262144
    u32* cnt    = (u32*)(ws + 1048576);          // 64
    u32* cntA   = (u32*)(ws + 1048640);          // 64
    u64* cut    = (u64*)(ws + 1048704);          // 128
    u16* smax16 = (u16*)(ws + 1048832);          // 806400 -> end 1855232
    u32* phist  = (u32*)(ws + 1855232);          // B*hblk*2048*4

    // hblk ladder: more k_hist blocks = more HBM MLP; pick largest that fits ws.
    int hblk = 16;
    if (ws_size >= (size_t)1855232 + (size_t)B * 128 * 2048 * 4) hblk = 128;
    else if (ws_size >= (size_t)1855232 + (size_t)B * 64 * 2048 * 4) hblk = 64;

    k_hist   <<<dim3(hblk, B), 256, 0, stream>>>(head, phist, smax16);
    k_redcut <<<B, 256, 0, stream>>>(phist, cut, hblk, cnt, cntA);
    k_screen <<<dim3((NA + 255) / 256, B), 256, 0, stream>>>(smax16, cut, cntA, alist);
    k_pairs  <<<dim3(PBLK, B), 256, 0, stream>>>(head, cut, cntA, alist, cnt, sb, si);
    k_snms   <<<B, 1024, 0, stream>>>(head, grid, ag, stv, cnt, sb, si, out);
}

// Round 15
// 220.444 us; speedup vs baseline: 1.6719x; 1.6719x over previous
//
#include <hip/hip_runtime.h>
#include <hip/hip_bf16.h>

#define B    16
#define NA   25200
#define NCH  85
#define NCLS 80
#define K    2048
#define CAP  4096
#define ACAP 4096
#define DET  300
#define TILE 64
#define NTILES 394                     // ceil(25200/64)
#define PBLK 64                        // k_pairs blocks per image
#define LBUF 2304                      // k_pairs LDS buffer
#define SBASE  0x3FD0000000000000ULL   // bits of 0.25 (double)
#define SSHIFT 42                      // -> 2048 bins over (0.25, 1.0)

typedef unsigned long long u64;
typedef unsigned int u32;
typedef unsigned short u16;

__device__ __forceinline__ double dsig(float x) { return 1.0 / (1.0 + exp(-(double)x)); }
__device__ __forceinline__ float  fsig(float x) { return 1.0f / (1.0f + __expf(-x)); }

// ---- Pass 1: full sweep with register-prefetch double buffering.
// Partial histograms (plain stores) + per-anchor u16 round-up max-score.
__global__ void __launch_bounds__(256) k_hist(const float* __restrict__ head,
                                              u32* __restrict__ phist, u16* __restrict__ smax16) {
    __shared__ float rows[TILE * NCH];     // 21760 B
    __shared__ int h[2048];                // 8192 B
    __shared__ float smaxT[TILE][4];       // 1024 B
    int tid = threadIdx.x;
    int hblk = gridDim.x;
    for (int i = tid; i < 2048; i += 256) h[i] = 0;
    int img = blockIdx.y;
    const float* ibase = head + (size_t)img * NA * NCH;

    float4 pf[6];
    int tile = blockIdx.x;
    {                                      // prefetch first tile
        int a0 = tile * TILE;
        int na = NA - a0; if (na > TILE) na = TILE;
        int nf4 = (na * NCH) >> 2;
        const float4* src = (const float4*)(ibase + (size_t)a0 * NCH);
        #pragma unroll
        for (int u = 0; u < 6; ++u) { int i = tid + u * 256; pf[u] = (i < nf4) ? src[i] : make_float4(0.f,0.f,0.f,0.f); }
    }
    for (; tile < NTILES; tile += hblk) {
        int a0 = tile * TILE;
        int na = NA - a0; if (na > TILE) na = TILE;
        int nf4 = (na * NCH) >> 2;
        __syncthreads();                   // prev iteration fully done with rows
        #pragma unroll
        for (int u = 0; u < 6; ++u) { int i = tid + u * 256; if (i < nf4) ((float4*)rows)[i] = pf[u]; }
        __syncthreads();
        int nt = tile + hblk;              // issue next tile's loads under compute
        if (nt < NTILES) {
            int a0n = nt * TILE;
            int nan_ = NA - a0n; if (nan_ > TILE) nan_ = TILE;
            int nf4n = (nan_ * NCH) >> 2;
            const float4* srcn = (const float4*)(ibase + (size_t)a0n * NCH);
            #pragma unroll
            for (int u = 0; u < 6; ++u) { int i = tid + u * 256; pf[u] = (i < nf4n) ? srcn[i] : make_float4(0.f,0.f,0.f,0.f); }
        }
        for (int t = tid; t < 4 * na; t += 256) {        // 4 threads per anchor
            int a = t >> 2, q = t & 3;
            float fo = fsig(rows[a * NCH + 4]);
            float lm = 0.0f;
            if (fo > 0.25f) {
                float qq = 0.24975f / fo;                         // (0.2497, 0.999)
                float cth = __logf(qq) - __logf(1.0f - qq);       // logit precheck
                int c0 = q * 20;
                for (int c = c0; c < c0 + 20; ++c) {
                    float cl = rows[a * NCH + 5 + c];
                    if (cl > cth) {
                        float sc = fo * fsig(cl);
                        lm = fmaxf(lm, sc);
                        if (sc > 0.25f) {
                            u64 bits = (u64)__double_as_longlong((double)sc);
                            int bb = (int)((bits - SBASE) >> SSHIFT);
                            if (bb > 2047) bb = 2047;
                            atomicAdd(&h[bb], 1);
                        }
                    }
                }
            }
            smaxT[a][q] = lm;
        }
        __syncthreads();
        for (int t = tid; t < na; t += 256) {
            float m = fmaxf(fmaxf(smaxT[t][0], smaxT[t][1]), fmaxf(smaxT[t][2], smaxT[t][3]));
            u32 mb = __float_as_uint(m);
            smax16[(size_t)img * NA + a0 + t] = (u16)((mb + 0xFFFFu) >> 16);  // round UP
        }
    }
    __syncthreads();
    u32* dst = phist + ((size_t)img * hblk + blockIdx.x) * 2048;
    for (int i = tid; i < 2048; i += 256) dst[i] = (u32)h[i];
}

// ---- Pass 2a: PARALLEL partial-histogram reduce. grid (B, 8): block (img,g)
// sums bins [g*256,(g+1)*256) across hblk partials (coalesced, independent
// loads). Also zeroes cnt/cntA (replaces memset dispatch). ----
__global__ void __launch_bounds__(256) k_redsum(const u32* __restrict__ phist,
                                                int* __restrict__ hist, int hblk,
                                                u32* __restrict__ cnt, u32* __restrict__ cntA) {
    int img = blockIdx.x;
    int bin = blockIdx.y * 256 + threadIdx.x;
    if (blockIdx.y == 0 && threadIdx.x == 0) cnt[img] = 0;
    if (blockIdx.y == 0 && threadIdx.x == 1) cntA[img] = 0;
    const u32* base = phist + (size_t)img * hblk * 2048 + bin;
    u32 s = 0;
    int p = 0;
    for (; p + 4 <= hblk; p += 4) {        // 4 independent loads in flight
        u32 a0 = base[(size_t)(p + 0) * 2048];
        u32 a1 = base[(size_t)(p + 1) * 2048];
        u32 a2 = base[(size_t)(p + 2) * 2048];
        u32 a3 = base[(size_t)(p + 3) * 2048];
        s += a0 + a1 + a2 + a3;
    }
    for (; p < hblk; ++p) s += base[(size_t)p * 2048];
    hist[img * 2048 + bin] = (int)s;
}

// ---- Pass 2b: cut-bin search, one wave per image (register preload) ----
__global__ void __launch_bounds__(1024) k_cut(const int* __restrict__ hist, u64* __restrict__ cut) {
    int lane = threadIdx.x & 63;
    int img  = threadIdx.x >> 6;           // 16 waves = 16 images
    const int* h = hist + img * 2048;
    int v[32];
    #pragma unroll
    for (int ch = 0; ch < 32; ++ch) v[ch] = h[2047 - ch * 64 - lane];
    int cum = 0; u64 cb = 0;
    #pragma unroll
    for (int ch = 0; ch < 32; ++ch) {
        int pfx = v[ch];
        for (int d = 1; d < 64; d <<= 1) { int o = __shfl_up(pfx, d, 64); if (lane >= d) pfx += o; }
        u64 ball = __ballot(cum + pfx >= K);
        if (ball) {
            int fl = __ffsll((long long)ball) - 1;
            int bin = 2047 - ch * 64 - fl;
            cb = (bin >= 1) ? (SBASE + ((u64)(bin - 1) << SSHIFT)) : 0ULL;  // one-bin margin
            break;
        }
        cum += __shfl(pfx, 63, 64);
    }
    if (lane == 0) cut[img] = cb;
}

// ---- Pass 3a: screen anchors by smax upper bound; compact survivor list ----
__global__ void __launch_bounds__(256) k_screen(const u16* __restrict__ smax16, const u64* __restrict__ cut,
                                                u32* __restrict__ cntA, int* __restrict__ alist) {
    __shared__ int lcnt, lbase, buf[256];
    int img = blockIdx.y;
    int a = blockIdx.x * 256 + threadIdx.x;
    if (threadIdx.x == 0) lcnt = 0;
    __syncthreads();
    u64 cutb = cut[img];
    float cutf = cutb ? (float)__longlong_as_double((long long)cutb) : 0.25f;
    float pre = fmaxf(0.2489f, cutf * 0.999f);
    if (a < NA) {
        float fup = __uint_as_float(((u32)smax16[(size_t)img * NA + a]) << 16);
        if (fup >= pre) buf[atomicAdd(&lcnt, 1)] = a;
    }
    __syncthreads();
    if (threadIdx.x == 0 && lcnt) lbase = atomicAdd(&cntA[img], (u32)lcnt);
    __syncthreads();
    for (int i = threadIdx.x; i < lcnt; i += 256) {
        int pos = lbase + i;
        if (pos < ACAP) alist[img * ACAP + pos] = buf[i];
    }
}

// ---- Pass 3b: pairs with per-block LDS compaction ----
__global__ void __launch_bounds__(256) k_pairs(const float* __restrict__ head, const u64* __restrict__ cut,
                                               const u32* __restrict__ cntA, const int* __restrict__ alist,
                                               u32* __restrict__ cnt, u64* __restrict__ sb, u32* __restrict__ si) {
    __shared__ u64 lsb[LBUF];
    __shared__ u32 lsi[LBUF];
    __shared__ u32 lcnt, lbase;
    int img = blockIdx.y;
    int tid = threadIdx.x;
    u64 cutb = cut[img];
    float cutf = cutb ? (float)__longlong_as_double((long long)cutb) : 0.25f;
    float pre = fmaxf(0.2489f, cutf * 0.999f);
    int nsur = (int)cntA[img]; if (nsur > ACAP) nsur = ACAP;
    int npairs = nsur * NCLS;
    u64* sbi = sb + (size_t)img * CAP;
    u32* sii = si + (size_t)img * CAP;
    const float* ibase = head + (size_t)img * NA * NCH;
    if (tid == 0) lcnt = 0;
    __syncthreads();

    int base = blockIdx.x * 256;
    int ntrip = (npairs > base) ? (npairs - base + PBLK * 256 - 1) / (PBLK * 256) : 0;
    for (int t = 0; t < ntrip; ++t) {
        int p = base + tid + t * PBLK * 256;
        if (p < npairs) {
            int ai = (int)((u32)p / NCLS);
            int c  = p - ai * NCLS;
            int a  = alist[img * ACAP + ai];
            const float* row = ibase + (size_t)a * NCH;
            float o = row[4], cl = row[5 + c];
            float s32 = fsig(o) * fsig(cl);
            if (s32 >= pre) {
                double sc = dsig(o) * dsig(cl);        // exact f64 decision
                if (sc > 0.25) {
                    u64 bits = (u64)__double_as_longlong(sc);
                    if (bits >= cutb) {
                        u32 pos = atomicAdd(&lcnt, 1u);
                        if (pos < LBUF) { lsb[pos] = bits; lsi[pos] = (u32)(a * NCLS + c); }
                    }
                }
            }
        }
        __syncthreads();
        if (lcnt >= 2048) {
            u32 n = lcnt; if (n > LBUF) n = LBUF;
            if (tid == 0) lbase = atomicAdd(&cnt[img], n);
            __syncthreads();
            for (u32 i = tid; i < n; i += 256) {
                u32 pos = lbase + i;
                if (pos < CAP) { sbi[pos] = lsb[i]; sii[pos] = lsi[i]; }
            }
            __syncthreads();
            if (tid == 0) lcnt = 0;
            __syncthreads();
        }
    }
    u32 n = lcnt; if (n > LBUF) n = LBUF;
    if (n) {
        if (tid == 0) lbase = atomicAdd(&cnt[img], n);
        __syncthreads();
        for (u32 i = tid; i < n; i += 256) {
            u32 pos = lbase + i;
            if (pos < CAP) { sbi[pos] = lsb[i]; sii[pos] = lsi[i]; }
        }
    }
}

// ---- Pass 4 (fused): counting sort -> decode (f64) -> SoA LDS offset boxes ->
// parallel stable seg build -> REGISTER-RESIDENT per-class wave greedy NMS
// (shfl broadcast, no LDS in loop) + cross-class cert (exact fallback) -> emit. ----
__global__ void __launch_bounds__(1024) k_snms(const float* __restrict__ head,
        const float* __restrict__ grid, const float* __restrict__ ag, const float* __restrict__ stv,
        const u32* __restrict__ cntArr, const u64* __restrict__ sb, const u32* __restrict__ si,
        float* __restrict__ out) {
    __shared__ double obm[4][K];      // 65536 B SoA; sort phase aliases inside
    __shared__ u64 mask[32], imask[32];
    __shared__ u16 labs[K];           // 4096 B
    __shared__ u16 seg[K];            // 4096 B (class-grouped slot ids, score order)
    __shared__ u32 chunkcnt[32][NCLS];// 10240 B: per-chunk class counts -> positions
    __shared__ int clsbase[NCLS + 1];
    __shared__ int clscnt[NCLS];
    __shared__ double red[16], red2[16];
    __shared__ double s_offb;
    __shared__ int wpfx[33];
    __shared__ int viol;
    __shared__ u32 segtot[32];

    int img = blockIdx.x;
    int tid = threadIdx.x;
    int lane = tid & 63, wv = tid >> 6;

    // sort-phase aliases inside obm: TA 32KB | TI 16KB | h2 8KB | cntb 8KB
    u64* TA   = (u64*)obm;            // [4096]
    u32* TI   = (u32*)(TA + 4096);    // [4096]
    u32* h2   = (u32*)(TI + 4096);    // [2048]
    u32* cntb = (u32*)(h2 + 2048);    // [2048]
    u32* tmp  = TI;                   // scan scratch (TI unused until scatter)

    const u64* A = sb + (size_t)img * CAP;
    const u32* I = si + (size_t)img * CAP;
    int cnt = (int)cntArr[img]; if (cnt > CAP) cnt = CAP;

    // 1. bin histogram of candidates (exact f64 top-11-bit bins)
    for (int b = tid; b < 2048; b += 1024) h2[b] = 0;
    __syncthreads();
    for (int e = tid; e < cnt; e += 1024) {
        u64 bits = A[e];
        int b = (int)((bits - SBASE) >> SSHIFT);
        b = b < 0 ? 0 : (b > 2047 ? 2047 : b);
        atomicAdd(&h2[b], 1u);
    }
    __syncthreads();
    // 2. suffix-sum -> start positions (descending bin order); snapshot counts
    for (int s = wv; s < 32; s += 16) {
        int r = s * 64 + lane;
        u32 v = h2[2047 - r];
        cntb[2047 - r] = v;
        u32 p = v;
        for (int d = 1; d < 64; d <<= 1) { u32 o = __shfl_up(p, d, 64); if (lane >= d) p += o; }
        if (lane == 63) segtot[s] = p;
        tmp[r] = p - v;
    }
    __syncthreads();
    if (tid < 32) {
        u32 v = segtot[tid], p = v;
        for (int d = 1; d < 32; d <<= 1) { u32 o = __shfl_up(p, d, 64); if (lane >= d) p += o; }
        segtot[tid] = p - v;
    }
    __syncthreads();
    for (int s = wv; s < 32; s += 16) {
        int r = s * 64 + lane;
        h2[2047 - r] = tmp[r] + segtot[s];
    }
    __syncthreads();
    // 3. init pad + scatter (within-bin order arbitrary)
    for (int e = tid; e < 4096; e += 1024) if (e >= cnt) { TA[e] = 0ULL; TI[e] = 0xFFFFFFFFu; }
    __syncthreads();
    for (int e = tid; e < cnt; e += 1024) {
        u64 bits = A[e]; u32 idx = I[e];
        int b = (int)((bits - SBASE) >> SSHIFT);
        b = b < 0 ? 0 : (b > 2047 ? 2047 : b);
        u32 slot = atomicAdd(&h2[b], 1u);
        if (slot < 4096u) { TA[slot] = bits; TI[slot] = idx; }
    }
    __syncthreads();
    // 4. parallel in-bin rank: each element finds its exact sorted slot
    u64 rb[4]; u32 ri[4]; int rp[4];
    #pragma unroll
    for (int s4 = 0; s4 < 4; ++s4) {
        int p = tid + s4 * 1024;
        rp[s4] = -1;
        if (p < cnt) {
            u64 kb = TA[p]; u32 ki = TI[p];
            int b = (int)((kb - SBASE) >> SSHIFT);
            b = b < 0 ? 0 : (b > 2047 ? 2047 : b);
            int en = (int)h2[b];
            int st = en - (int)cntb[b];
            int r = st;
            for (int j = st; j < en; ++j) {
                u64 b2 = TA[j]; u32 i2 = TI[j];
                if (b2 > kb || (b2 == kb && i2 < ki)) ++r;
            }
            rb[s4] = kb; ri[s4] = ki; rp[s4] = r;
        }
    }
    __syncthreads();
    #pragma unroll
    for (int s4 = 0; s4 < 4; ++s4)
        if (rp[s4] >= 0 && rp[s4] < 4096) { TA[rp[s4]] = rb[s4]; TI[rp[s4]] = ri[s4]; }
    __syncthreads();
    // 5. top-2048 to registers
    u64 sv[2]; u32 fidx[2];
    sv[0] = TA[tid];        fidx[0] = TI[tid];
    sv[1] = TA[1024 + tid]; fidx[1] = TI[1024 + tid];
    __syncthreads();                    // TA/TI dead; obm reusable

    // --- decode (exact f64) + chunk class counts ---
    if (tid < NCLS) clscnt[tid] = 0;
    if (tid == 0) viol = 0;
    for (int i = tid; i < 32 * NCLS; i += 1024) ((u32*)chunkcnt)[i] = 0;
    double bx[2][4];
    int lab[2];
    bool val[2];
    double lmax = -1e300, lmin = 1e300;
    __syncthreads();
    #pragma unroll
    for (int q = 0; q < 2; ++q) {
        int slot = q * 1024 + tid;
        val[q] = (sv[q] != 0ULL);
        bx[q][0] = bx[q][1] = bx[q][2] = bx[q][3] = 0.0;
        lab[q] = 0;
        if (val[q]) {
            int a = (int)(fidx[q] / NCLS);
            lab[q] = (int)(fidx[q] % NCLS);
            const float* row = head + ((size_t)img * NA + a) * NCH;
            double p0 = dsig(row[0]), p1 = dsig(row[1]), p2 = dsig(row[2]), p3 = dsig(row[3]);
            double st = (double)stv[a];
            double xc = (p0 * 2.0 - 0.5 + (double)grid[a * 2 + 0]) * st;
            double yc = (p1 * 2.0 - 0.5 + (double)grid[a * 2 + 1]) * st;
            double w = p2 * 2.0; w = (w * w) * (double)ag[a * 2 + 0];
            double h = p3 * 2.0; h = (h * h) * (double)ag[a * 2 + 1];
            bx[q][0] = xc - w * 0.5; bx[q][1] = yc - h * 0.5;
            bx[q][2] = xc + w * 0.5; bx[q][3] = yc + h * 0.5;
            lmax = fmax(lmax, fmax(fmax(bx[q][0], bx[q][1]), fmax(bx[q][2], bx[q][3])));
            lmin = fmin(lmin, fmin(fmin(bx[q][0], bx[q][1]), fmin(bx[q][2], bx[q][3])));
            atomicAdd(&clscnt[lab[q]], 1);
            atomicAdd(&chunkcnt[slot >> 6][lab[q]], 1u);
        }
        labs[slot] = val[q] ? (u16)lab[q] : (u16)0xFFFF;
    }
    for (int d = 1; d < 64; d <<= 1) {
        lmax = fmax(lmax, __shfl_xor(lmax, d, 64));
        lmin = fmin(lmin, __shfl_xor(lmin, d, 64));
    }
    if (lane == 0) { red[wv] = lmax; red2[wv] = lmin; }
    u64 b0m = __ballot(val[0]), b1m = __ballot(val[1]);
    if (lane == 0) { mask[wv] = b0m; imask[wv] = b0m; mask[16 + wv] = b1m; imask[16 + wv] = b1m; }
    __syncthreads();
    if (tid == 0) {
        double m = red[0], mn = red2[0];
        for (int w2 = 1; w2 < 16; ++w2) { m = fmax(m, red[w2]); mn = fmin(mn, red2[w2]); }
        s_offb = m + 1.0;
        if (m + 2.0 + mn < 0.0) viol = 1;   // |dclass|>=2 overlap possible -> fallback
    }
    __syncthreads();
    double offb = s_offb;

    double oB[2][4], aR[2];
    #pragma unroll
    for (int q = 0; q < 2; ++q) {
        double off = offb * (double)lab[q];
        oB[q][0] = bx[q][0] + off; oB[q][1] = bx[q][1] + off;
        oB[q][2] = bx[q][2] + off; oB[q][3] = bx[q][3] + off;
        aR[q] = (oB[q][2] - oB[q][0]) * (oB[q][3] - oB[q][1]);
        int slot = q * 1024 + tid;
        obm[0][slot] = oB[q][0]; obm[1][slot] = oB[q][1];
        obm[2][slot] = oB[q][2]; obm[3][slot] = oB[q][3];
    }
    __syncthreads();

    // class-count exclusive scan -> clsbase[0..80]
    if (tid < 64) {
        int c0 = clscnt[lane];
        int c1 = (lane < NCLS - 64) ? clscnt[64 + lane] : 0;
        int p0 = c0;
        for (int d = 1; d < 64; d <<= 1) { int o = __shfl_up(p0, d, 64); if (lane >= d) p0 += o; }
        int tot0 = __shfl(p0, 63, 64);
        int p1 = c1;
        for (int d = 1; d < 64; d <<= 1) { int o = __shfl_up(p1, d, 64); if (lane >= d) p1 += o; }
        clsbase[lane] = p0 - c0;
        if (lane < NCLS - 64) clsbase[64 + lane] = tot0 + p1 - c1;
        if (lane == 63) clsbase[NCLS] = tot0 + __shfl(p1, NCLS - 64 - 1, 64);
    }
    __syncthreads();

    // chunkcnt -> chunk start positions (per class, chunks in slot order)
    if (tid < NCLS) {
        int running = clsbase[tid];
        for (int ch = 0; ch < 32; ++ch) {
            u32 t = chunkcnt[ch][tid];
            chunkcnt[ch][tid] = (u32)running;
            running += (int)t;
        }
    }
    __syncthreads();

    // stable seg build: rank within own chunk via shfl_up compare loop
    #pragma unroll
    for (int q = 0; q < 2; ++q) {
        int cl = val[q] ? lab[q] : -1;
        int rank = 0;
        for (int d = 1; d < 64; ++d) {
            int oc = __shfl_up(cl, d, 64);
            if (lane >= d && oc == cl) ++rank;
        }
        if (val[q]) {
            int slot = q * 1024 + tid;
            seg[chunkcnt[slot >> 6][cl] + rank] = (u16)slot;
        }
    }
    __syncthreads();

    // --- per-class greedy (one wave per class; register-resident, shfl broadcast) ---
    for (int k5 = 0; k5 < 5; ++k5) {
        int c = wv * 5 + k5;
        int cbase = clsbase[c];
        int m = clsbase[c + 1] - cbase;
        if (m <= 1) continue;
        if (m <= 64) {
            int s_l = (lane < m) ? (int)seg[cbase + lane] : -1;
            double e0 = 0, e1 = 0, e2 = 0, e3 = 0, ea = 0;
            if (s_l >= 0) {
                e0 = obm[0][s_l]; e1 = obm[1][s_l];
                e2 = obm[2][s_l]; e3 = obm[3][s_l];
                ea = (e2 - e0) * (e3 - e1);
            }
            u64 am = (m >= 64) ? ~0ULL : ((1ULL << m) - 1ULL);
            for (int k = 0; k < m; ++k) {
                if (!((am >> k) & 1ULL)) continue;          // uniform (am uniform)
                double k0 = __shfl(e0, k, 64), k1 = __shfl(e1, k, 64);
                double k2 = __shfl(e2, k, 64), k3 = __shfl(e3, k, 64);
                double ka = __shfl(ea, k, 64);
                double ww = fmax(fmin(k2, e2) - fmax(k0, e0), 0.0);
                double hh = fmax(fmin(k3, e3) - fmax(k1, e1), 0.0);
                double inter = ww * hh;
                bool sup = (lane > k) && ((am >> lane) & 1ULL) &&
                           (inter > 0.45 * (ka + ea - inter + 1e-7));
                am &= ~__ballot(sup);
            }
            if (s_l >= 0 && !((am >> lane) & 1ULL))
                atomicAnd(&mask[s_l >> 6], ~(1ULL << (s_l & 63)));
        } else {
            // LDS fallback for oversized classes (rare)
            for (int k = cbase + 1; k < cbase + m; ++k) {
                int s = (int)seg[k];
                double c0 = obm[0][s], c1 = obm[1][s];
                double c2v = obm[2][s], c3 = obm[3][s];
                double ca = (c2v - c0) * (c3 - c1);
                bool sup = false;
                for (int j = cbase + lane; j < k; j += 64) {
                    int t = (int)seg[j];
                    if ((mask[t >> 6] >> (t & 63)) & 1ULL) {
                        double b0 = obm[0][t], b1 = obm[1][t];
                        double b2 = obm[2][t], b3 = obm[3][t];
                        double ww = fmax(fmin(c2v, b2) - fmax(c0, b0), 0.0);
                        double hh = fmax(fmin(c3, b3) - fmax(c1, b1), 0.0);
                        double inter = ww * hh;
                        double aj = (b2 - b0) * (b3 - b1);
                        if (inter > 0.45 * (ca + aj - inter + 1e-7)) sup = true;
                    }
                }
                if (__ballot(sup)) {
                    if (lane == 0) atomicAnd(&mask[s >> 6], ~(1ULL << (s & 63)));
                }
            }
        }
    }
    __syncthreads();

    // --- certification vs adjacent classes (conservative 0.42 f32) ---
    #pragma unroll
    for (int q = 0; q < 2; ++q) {
        int s = q * 1024 + tid;
        if ((mask[s >> 6] >> (s & 63)) & 1ULL) {
            int myc = (int)labs[s];
            float c0 = (float)obm[0][s], c1 = (float)obm[1][s];
            float c2v = (float)obm[2][s], c3 = (float)obm[3][s];
            float ca = (c2v - c0) * (c3 - c1);
            #pragma unroll
            for (int dd = 0; dd < 2; ++dd) {
                int cc = myc + (dd ? 1 : -1);
                if (cc < 0 || cc >= NCLS) continue;
                int je = clsbase[cc + 1];
                for (int j = clsbase[cc]; j < je; ++j) {
                    int t = (int)seg[j];
                    if (t > s) {
                        float b0 = (float)obm[0][t], b1 = (float)obm[1][t];
                        float b2 = (float)obm[2][t], b3 = (float)obm[3][t];
                        float ww = fmaxf(fminf(c2v, b2) - fmaxf(c0, b0), 0.f);
                        float hh = fmaxf(fminf(c3, b3) - fmaxf(c1, b1), 0.f);
                        float inter = ww * hh;
                        float aj = (b2 - b0) * (b3 - b1);
                        if (inter > 0.42f * (ca + aj - inter + 1e-7f)) viol = 1;
                    }
                }
            }
        }
    }
    __syncthreads();

    // --- fallback: exact sequential greedy (cold; cert guarantees exactness) ---
    if (viol) {
        if (tid < 32) mask[tid] = imask[tid];
        bool alive[2]; alive[0] = val[0]; alive[1] = val[1];
        __syncthreads();
        int i = -1, kc = 0;
        while (true) {
            int start = i + 1;
            if (start >= K) break;
            int w = start >> 6;
            u64 m = mask[w] & (~0ULL << (start & 63));
            while (m == 0ULL) { if (++w >= 32) break; m = mask[w]; }
            if (w >= 32) break;
            i = (w << 6) + __ffsll((long long)m) - 1;
            ++kc;
            if (kc >= DET) break;
            double bi0 = obm[0][i], bi1 = obm[1][i];
            double bi2 = obm[2][i], bi3 = obm[3][i];
            double ai = (bi2 - bi0) * (bi3 - bi1);
            #pragma unroll
            for (int q = 0; q < 2; ++q) {
                int slot = q * 1024 + tid;
                double w_ = fmax(fmin(bi2, oB[q][2]) - fmax(bi0, oB[q][0]), 0.0);
                double h_ = fmax(fmin(bi3, oB[q][3]) - fmax(bi1, oB[q][1]), 0.0);
                double inter = w_ * h_;
                bool sup = inter > 0.45 * (ai + aR[q] - inter + 1e-7);
                if (alive[q] && slot > i && sup) {
                    alive[q] = false;
                    atomicAnd(&mask[slot >> 6], ~(1ULL << (slot & 63)));
                }
            }
            __syncthreads();
        }
        __syncthreads();
    }

    // --- emit ---
    if (tid == 0) {
        int s = 0;
        for (int w2 = 0; w2 < 32; ++w2) { wpfx[w2] = s; s += __popcll(mask[w2]); }
        wpfx[32] = s;
    }
    __syncthreads();
    int total = wpfx[32]; if (total > DET) total = DET;

    float* bo  = out + (size_t)img * DET * 4;
    float* so_ = out + (size_t)B * DET * 4 + (size_t)img * DET;
    float* lo  = out + (size_t)B * DET * 5 + (size_t)img * DET;
    #pragma unroll
    for (int q = 0; q < 2; ++q) {
        int slot = q * 1024 + tid;
        int w = slot >> 6, bpos = slot & 63;
        if ((mask[w] >> bpos) & 1ULL) {
            int r = wpfx[w] + __popcll(mask[w] & ((1ULL << bpos) - 1ULL));
            if (r < DET) {
                bo[r * 4 + 0] = (float)bx[q][0]; bo[r * 4 + 1] = (float)bx[q][1];
                bo[r * 4 + 2] = (float)bx[q][2]; bo[r * 4 + 3] = (float)bx[q][3];
                so_[r] = (float)__longlong_as_double((long long)sv[q]);
                lo[r] = (float)lab[q];
            }
        }
    }
    if (tid >= total && tid < DET) {
        bo[tid * 4 + 0] = 0.f; bo[tid * 4 + 1] = 0.f;
        bo[tid * 4 + 2] = 0.f; bo[tid * 4 + 3] = 0.f;
        so_[tid] = -1.0f; lo[tid] = -1.0f;
    }
}

extern "C" void kernel_launch(void* const* d_in, const int* in_sizes, int n_in,
                              void* d_out, int out_size, void* d_ws, size_t ws_size,
                              hipStream_t stream) {
    const float* head = (const float*)d_in[0];   // [16,25200,85]
    const float* grid = (const float*)d_in[1];   // [25200,2]
    const float* ag   = (const float*)d_in[2];   // [25200,2]
    const float* stv  = (const float*)d_in[3];   // [25200,1]
    float* out = (float*)d_out;
    char* ws = (char*)d_ws;

    u64* sb     = (u64*)(ws + 0);                // 16*4096*8 = 524288
    u32* si     = (u32*)(ws + 524288);           // 262144
    int* alist  = (int*)(ws + 786432);           // 262144
    u32* cnt    = (u32*)(ws + 1048576);          // 64
    u32* cntA   = (u32*)(ws + 1048640);          // 64
    u64* cut    = (u64*)(ws + 1048704);          // 128
    u16* smax16 = (u16*)(ws + 1048832);          // 806400 -> end 1855232
    int* hist   = (int*)(ws + 1855232);          // 16*2048*4 = 131072 -> 1986304
    u32* phist  = (u32*)(ws + 1986304);          // B*hblk*2048*4

    // hblk ladder: more k_hist blocks = more HBM MLP; reduce is now parallel.
    int hblk = 16;
    if (ws_size >= (size_t)1986304 + (size_t)B * 128 * 2048 * 4) hblk = 128;
    else if (ws_size >= (size_t)1986304 + (size_t)B * 64 * 2048 * 4) hblk = 64;

    k_hist   <<<dim3(hblk, B), 256, 0, stream>>>(head, phist, smax16);
    k_redsum <<<dim3(B, 8), 256, 0, stream>>>(phist, hist, hblk, cnt, cntA);
    k_cut    <<<1, 1024, 0, stream>>>(hist, cut);
    k_screen <<<dim3((NA + 255) / 256, B), 256, 0, stream>>>(smax16, cut, cntA, alist);
    k_pairs  <<<dim3(PBLK, B), 256, 0, stream>>>(head, cut, cntA, alist, cnt, sb, si);
    k_snms   <<<B, 1024, 0, stream>>>(head, grid, ag, stv, cnt, sb, si, out);
}